// Round 1
// baseline (402.312 us; speedup 1.0000x reference)
//
#include <hip/hip_runtime.h>

// Problem constants (from reference)
#define NN 8192
#define IN_DIM 512
#define NUM_CLASSES 16
#define PER_CLASS 512
#define KK 256
#define NSEL (NUM_CLASSES * KK)   // 4096

// ---------------------------------------------------------------------------
// Kernel 1: scores[i] = sigmoid((dot(X[i], W) + b) / 100)
// One wave (64 lanes) per row; each lane handles 2 float4s (8 elements).
// ---------------------------------------------------------------------------
__global__ __launch_bounds__(256) void scores_kernel(
    const float* __restrict__ X, const float* __restrict__ W,
    const float* __restrict__ b, float* __restrict__ scores) {
  const int wave = threadIdx.x >> 6;
  const int lane = threadIdx.x & 63;
  const int row  = blockIdx.x * (blockDim.x >> 6) + wave;
  if (row >= NN) return;

  const float4* xp = (const float4*)(X + (size_t)row * IN_DIM);
  const float4* wp = (const float4*)W;
  float acc = 0.f;
#pragma unroll
  for (int k = 0; k < 2; ++k) {
    const int i = lane + k * 64;   // 128 float4s per row
    const float4 xv = xp[i];
    const float4 wv = wp[i];
    acc += xv.x * wv.x + xv.y * wv.y + xv.z * wv.z + xv.w * wv.w;
  }
#pragma unroll
  for (int off = 32; off > 0; off >>= 1)
    acc += __shfl_xor(acc, off, 64);

  if (lane == 0) {
    const float z = (acc + b[0]) * 0.01f;
    scores[row] = 1.0f / (1.0f + expf(-z));
  }
}

// ---------------------------------------------------------------------------
// Kernel 2: per-class selection. 16 blocks (one per class) x 512 threads.
// Phase A: member list (global indices of this class, ascending) via
//          chunked ballot + block prefix sum.
// Phase B: mean of the 512 member scores (double accumulate -> float).
// Phase C: exact top_k order replication: key = mean - score, sort
//          descending, ties by lower position. Rank via O(n^2) counting
//          (LDS broadcast reads, uniform inner loop -> conflict-free).
// ---------------------------------------------------------------------------
__global__ __launch_bounds__(512) void select_kernel(
    const int* __restrict__ mask, const float* __restrict__ scores,
    int* __restrict__ sel_idx, float* __restrict__ sel_val) {
  const int cls  = blockIdx.x;
  const int tid  = threadIdx.x;
  const int lane = tid & 63;
  const int wave = tid >> 6;     // 8 waves

  __shared__ int   members[PER_CLASS];
  __shared__ float ssc[PER_CLASS];
  __shared__ int   wave_tot[8];
  __shared__ int   running;
  __shared__ double wsum[8];
  __shared__ float meanf;

  if (tid == 0) running = 0;
  __syncthreads();

  // Phase A: gather member indices in ascending order
  for (int chunk = 0; chunk < NN; chunk += 512) {
    const int i = chunk + tid;
    const bool flag = (mask[i] == cls);
    const unsigned long long bal = __ballot(flag);
    const int pre = __popcll(bal & ((1ull << lane) - 1ull));
    if (lane == 0) wave_tot[wave] = __popcll(bal);
    __syncthreads();
    int woff = 0;
    for (int w = 0; w < wave; ++w) woff += wave_tot[w];
    const int pos = running + woff + pre;
    if (flag) members[pos] = i;
    __syncthreads();           // everyone done reading `running`
    if (tid == 0) {
      int tot = 0;
      for (int w = 0; w < 8; ++w) tot += wave_tot[w];
      running += tot;
    }
    __syncthreads();           // updated `running` visible next chunk
  }

  // Phase B: member scores + mean
  ssc[tid] = scores[members[tid]];
  __syncthreads();
  double v = (double)ssc[tid];
#pragma unroll
  for (int off = 32; off > 0; off >>= 1)
    v += __shfl_xor(v, off, 64);
  if (lane == 0) wsum[wave] = v;
  __syncthreads();
  if (tid == 0) {
    double s = 0.0;
    for (int w = 0; w < 8; ++w) s += wsum[w];
    meanf = (float)(s / (double)PER_CLASS);
  }
  __syncthreads();

  // Phase C: rank by (key desc, position asc) — exact lax.top_k order
  const float m = meanf;
  const float mykey = m - ssc[tid];
  int rank = 0;
  for (int u = 0; u < PER_CLASS; ++u) {
    const float ku = m - ssc[u];
    rank += (ku > mykey) || (ku == mykey && u < tid);
  }
  if (rank < KK) {
    sel_val[cls * KK + rank] = ssc[tid];
    sel_idx[cls * KK + rank] = members[tid];
  }
}

// ---------------------------------------------------------------------------
// Kernel 3: X_out[r] = X[idx[r]] * values[r]; also mask_out[r] = mask[idx[r]]
// One block of 128 threads per output row; float4 in/out (512 floats/row).
// ---------------------------------------------------------------------------
__global__ __launch_bounds__(128) void xout_kernel(
    const float* __restrict__ X, const int* __restrict__ mask,
    const int* __restrict__ sel_idx, const float* __restrict__ sel_val,
    float* __restrict__ xout, float* __restrict__ maskout) {
  const int r   = blockIdx.x;
  const int src = sel_idx[r];
  const float v = sel_val[r];
  const float4* xp = (const float4*)(X + (size_t)src * IN_DIM);
  float4* op = (float4*)(xout + (size_t)r * IN_DIM);
  const float4 x = xp[threadIdx.x];
  op[threadIdx.x] = make_float4(x.x * v, x.y * v, x.z * v, x.w * v);
  if (threadIdx.x == 0) maskout[r] = (float)mask[src];
}

// ---------------------------------------------------------------------------
// Kernel 4: M_out[r][c] = M[idx[r]][idx[c]].
// One block per output row: stage the full 32 KB source row coalesced into
// LDS, then gather 4096 columns from LDS and store coalesced float4.
// 32 KB LDS -> 5 blocks/CU.
// ---------------------------------------------------------------------------
__global__ __launch_bounds__(256) void mout_kernel(
    const float* __restrict__ M, const int* __restrict__ sel_idx,
    float* __restrict__ mout) {
  __shared__ float row[NN];    // 32 KB
  const int r = blockIdx.x;
  const int srcrow = sel_idx[r];

  const float4* mp = (const float4*)(M + (size_t)srcrow * NN);
  float4* rp = (float4*)row;
#pragma unroll
  for (int k = 0; k < (NN / 4) / 256; ++k) {   // 8 iters
    const int i = k * 256 + threadIdx.x;
    rp[i] = mp[i];
  }
  __syncthreads();

  float4* out = (float4*)(mout + (size_t)r * NSEL);
  const int4* idx4 = (const int4*)sel_idx;
#pragma unroll
  for (int k = 0; k < 4; ++k) {                // 4 x 1024 cols
    const int c4 = k * 256 + threadIdx.x;      // float4 index
    const int4 id = idx4[c4];
    out[c4] = make_float4(row[id.x], row[id.y], row[id.z], row[id.w]);
  }
}

// ---------------------------------------------------------------------------
extern "C" void kernel_launch(void* const* d_in, const int* in_sizes, int n_in,
                              void* d_out, int out_size, void* d_ws, size_t ws_size,
                              hipStream_t stream) {
  const float* M    = (const float*)d_in[0];   // [1,8192,8192]
  const float* X    = (const float*)d_in[1];   // [1,8192,512]
  const int*   mask = (const int*)  d_in[2];   // [1,8192]
  const float* W    = (const float*)d_in[3];   // [1,512]
  const float* b    = (const float*)d_in[4];   // [1]

  float* out = (float*)d_out;
  // Output layout (flat, return order): M_out | X_out | mask_out
  float* m_out    = out;                                   // 4096*4096
  float* x_out    = out + (size_t)NSEL * NSEL;             // 4096*512
  float* mask_out = x_out + (size_t)NSEL * IN_DIM;         // 4096

  // Workspace layout
  float* scores  = (float*)d_ws;                            // 8192 f
  int*   sel_idx = (int*)((char*)d_ws + NN * sizeof(float));        // 4096 i
  float* sel_val = (float*)((char*)d_ws + NN * sizeof(float)
                                        + NSEL * sizeof(int));      // 4096 f

  // 1) scores: 4 waves/block -> 4 rows/block -> 2048 blocks
  scores_kernel<<<NN / 4, 256, 0, stream>>>(X, W, b, scores);

  // 2) per-class top-k selection
  select_kernel<<<NUM_CLASSES, 512, 0, stream>>>(mask, scores, sel_idx, sel_val);

  // 3) X gather+scale and mask gather
  xout_kernel<<<NSEL, 128, 0, stream>>>(X, mask, sel_idx, sel_val, x_out, mask_out);

  // 4) M double-gather
  mout_kernel<<<NSEL, 256, 0, stream>>>(M, sel_idx, m_out);
}

// Round 3
// 387.756 us; speedup vs baseline: 1.0375x; 1.0375x over previous
//
#include <hip/hip_runtime.h>

// Problem constants (from reference)
#define NN 8192
#define IN_DIM 512
#define NUM_CLASSES 16
#define PER_CLASS 512
#define KK 256
#define NSEL (NUM_CLASSES * KK)   // 4096

// Native clang vector type — accepted by __builtin_nontemporal_* (HIP's
// float4 is a class and is rejected).
typedef float vfloat4 __attribute__((ext_vector_type(4)));

// ---------------------------------------------------------------------------
// Kernel 1: scores[i] = sigmoid((dot(X[i], W) + b) / 100)
// One wave (64 lanes) per row; each lane handles 2 float4s (8 elements).
// ---------------------------------------------------------------------------
__global__ __launch_bounds__(256) void scores_kernel(
    const float* __restrict__ X, const float* __restrict__ W,
    const float* __restrict__ b, float* __restrict__ scores) {
  const int wave = threadIdx.x >> 6;
  const int lane = threadIdx.x & 63;
  const int row  = blockIdx.x * (blockDim.x >> 6) + wave;
  if (row >= NN) return;

  const float4* xp = (const float4*)(X + (size_t)row * IN_DIM);
  const float4* wp = (const float4*)W;
  float acc = 0.f;
#pragma unroll
  for (int k = 0; k < 2; ++k) {
    const int i = lane + k * 64;   // 128 float4s per row
    const float4 xv = xp[i];
    const float4 wv = wp[i];
    acc += xv.x * wv.x + xv.y * wv.y + xv.z * wv.z + xv.w * wv.w;
  }
#pragma unroll
  for (int off = 32; off > 0; off >>= 1)
    acc += __shfl_xor(acc, off, 64);

  if (lane == 0) {
    const float z = (acc + b[0]) * 0.01f;
    scores[row] = 1.0f / (1.0f + expf(-z));
  }
}

// ---------------------------------------------------------------------------
// Kernel 2: per-class selection. 16 blocks (one per class) x 512 threads.
// Phase A: member list (ascending) via chunked ballot + block prefix sum.
// Phase B: mean of the 512 member scores (double accumulate -> float).
// Phase C: exact top_k order: key = mean - score desc, ties by position asc.
//          O(n^2) rank-by-counting; LDS broadcast reads, conflict-free.
// ---------------------------------------------------------------------------
__global__ __launch_bounds__(512) void select_kernel(
    const int* __restrict__ mask, const float* __restrict__ scores,
    int* __restrict__ sel_idx, float* __restrict__ sel_val) {
  const int cls  = blockIdx.x;
  const int tid  = threadIdx.x;
  const int lane = tid & 63;
  const int wave = tid >> 6;     // 8 waves

  __shared__ int   members[PER_CLASS];
  __shared__ float ssc[PER_CLASS];
  __shared__ int   wave_tot[8];
  __shared__ int   running;
  __shared__ double wsum[8];
  __shared__ float meanf;

  if (tid == 0) running = 0;
  __syncthreads();

  // Phase A: gather member indices in ascending order
  for (int chunk = 0; chunk < NN; chunk += 512) {
    const int i = chunk + tid;
    const bool flag = (mask[i] == cls);
    const unsigned long long bal = __ballot(flag);
    const int pre = __popcll(bal & ((1ull << lane) - 1ull));
    if (lane == 0) wave_tot[wave] = __popcll(bal);
    __syncthreads();
    int woff = 0;
    for (int w = 0; w < wave; ++w) woff += wave_tot[w];
    const int pos = running + woff + pre;
    if (flag) members[pos] = i;
    __syncthreads();           // everyone done reading `running`
    if (tid == 0) {
      int tot = 0;
      for (int w = 0; w < 8; ++w) tot += wave_tot[w];
      running += tot;
    }
    __syncthreads();           // updated `running` visible next chunk
  }

  // Phase B: member scores + mean
  ssc[tid] = scores[members[tid]];
  __syncthreads();
  double v = (double)ssc[tid];
#pragma unroll
  for (int off = 32; off > 0; off >>= 1)
    v += __shfl_xor(v, off, 64);
  if (lane == 0) wsum[wave] = v;
  __syncthreads();
  if (tid == 0) {
    double s = 0.0;
    for (int w = 0; w < 8; ++w) s += wsum[w];
    meanf = (float)(s / (double)PER_CLASS);
  }
  __syncthreads();

  // Phase C: rank by (key desc, position asc) — exact lax.top_k order
  const float m = meanf;
  const float mykey = m - ssc[tid];
  int rank = 0;
  for (int u = 0; u < PER_CLASS; ++u) {
    const float ku = m - ssc[u];
    rank += (ku > mykey) || (ku == mykey && u < tid);
  }
  if (rank < KK) {
    sel_val[cls * KK + rank] = ssc[tid];
    sel_idx[cls * KK + rank] = members[tid];
  }
}

// ---------------------------------------------------------------------------
// Kernel 3 (fused): one block per output row r.
//   M_out[r][c] = M[idx[r]][idx[c]]  (stage 32 KB row in LDS, gather, store)
//   X_out[r]    = X[idx[r]] * val[r] (issued before the barrier -> overlaps)
//   mask_out[r] = mask[idx[r]]
// Nontemporal on the read-once/write-once streams to spare L2/L3.
// ---------------------------------------------------------------------------
__global__ __launch_bounds__(256) void gather_kernel(
    const float* __restrict__ M, const float* __restrict__ X,
    const int* __restrict__ mask, const int* __restrict__ sel_idx,
    const float* __restrict__ sel_val, float* __restrict__ m_out,
    float* __restrict__ x_out, float* __restrict__ mask_out) {
  __shared__ float row[NN];    // 32 KB
  const int r   = blockIdx.x;
  const int src = sel_idx[r];

  // Stage M row (32 KB, coalesced, read-once -> nontemporal)
  const vfloat4* mp = (const vfloat4*)(M + (size_t)src * NN);
  vfloat4* rp = (vfloat4*)row;
#pragma unroll
  for (int k = 0; k < 8; ++k) {
    const int i = k * 256 + threadIdx.x;
    rp[i] = __builtin_nontemporal_load(&mp[i]);
  }

  // X row gather+scale (2 KB) — overlaps the M stage, before the barrier
  if (threadIdx.x < 128) {
    const float v = sel_val[r];
    const vfloat4 x =
        ((const vfloat4*)(X + (size_t)src * IN_DIM))[threadIdx.x];
    const vfloat4 o = x * v;
    __builtin_nontemporal_store(
        o, (vfloat4*)(x_out + (size_t)r * IN_DIM) + threadIdx.x);
  }
  if (threadIdx.x == 0) mask_out[r] = (float)mask[src];

  __syncthreads();

  // Gather 4096 columns from LDS, store coalesced float4 (write-once)
  vfloat4* out = (vfloat4*)(m_out + (size_t)r * NSEL);
  const int4* idx4 = (const int4*)sel_idx;
#pragma unroll
  for (int k = 0; k < 4; ++k) {
    const int c4 = k * 256 + threadIdx.x;      // float4 index
    const int4 id = idx4[c4];
    vfloat4 o;
    o.x = row[id.x]; o.y = row[id.y]; o.z = row[id.z]; o.w = row[id.w];
    __builtin_nontemporal_store(o, &out[c4]);
  }
}

// ---------------------------------------------------------------------------
extern "C" void kernel_launch(void* const* d_in, const int* in_sizes, int n_in,
                              void* d_out, int out_size, void* d_ws, size_t ws_size,
                              hipStream_t stream) {
  const float* M    = (const float*)d_in[0];   // [1,8192,8192]
  const float* X    = (const float*)d_in[1];   // [1,8192,512]
  const int*   mask = (const int*)  d_in[2];   // [1,8192]
  const float* W    = (const float*)d_in[3];   // [1,512]
  const float* b    = (const float*)d_in[4];   // [1]

  float* out = (float*)d_out;
  // Output layout (flat, return order): M_out | X_out | mask_out
  float* m_out    = out;                                   // 4096*4096
  float* x_out    = out + (size_t)NSEL * NSEL;             // 4096*512
  float* mask_out = x_out + (size_t)NSEL * IN_DIM;         // 4096

  // Workspace layout
  float* scores  = (float*)d_ws;                                    // 8192 f
  int*   sel_idx = (int*)((char*)d_ws + NN * sizeof(float));        // 4096 i
  float* sel_val = (float*)((char*)d_ws + NN * sizeof(float)
                                        + NSEL * sizeof(int));      // 4096 f

  // 1) scores: 4 waves/block -> 4 rows/block -> 2048 blocks
  scores_kernel<<<NN / 4, 256, 0, stream>>>(X, W, b, scores);

  // 2) per-class top-k selection
  select_kernel<<<NUM_CLASSES, 512, 0, stream>>>(mask, scores, sel_idx, sel_val);

  // 3) fused M/X/mask gather
  gather_kernel<<<NSEL, 256, 0, stream>>>(M, X, mask, sel_idx, sel_val,
                                          m_out, x_out, mask_out);
}

// Round 4
// 385.936 us; speedup vs baseline: 1.0424x; 1.0047x over previous
//
#include <hip/hip_runtime.h>

// Problem constants (from reference)
#define NN 8192
#define IN_DIM 512
#define NUM_CLASSES 16
#define PER_CLASS 512
#define KK 256
#define NSEL (NUM_CLASSES * KK)   // 4096

// Native clang vector type — accepted by __builtin_nontemporal_* (HIP's
// float4 is a class and is rejected).
typedef float vfloat4 __attribute__((ext_vector_type(4)));

// ---------------------------------------------------------------------------
// Kernel 1: scores[i] = sigmoid((dot(X[i], W) + b) / 100)
// One wave (64 lanes) per row; each lane handles 2 float4s (8 elements).
// ---------------------------------------------------------------------------
__global__ __launch_bounds__(256) void scores_kernel(
    const float* __restrict__ X, const float* __restrict__ W,
    const float* __restrict__ b, float* __restrict__ scores) {
  const int wave = threadIdx.x >> 6;
  const int lane = threadIdx.x & 63;
  const int row  = blockIdx.x * (blockDim.x >> 6) + wave;
  if (row >= NN) return;

  const float4* xp = (const float4*)(X + (size_t)row * IN_DIM);
  const float4* wp = (const float4*)W;
  float acc = 0.f;
#pragma unroll
  for (int k = 0; k < 2; ++k) {
    const int i = lane + k * 64;   // 128 float4s per row
    const float4 xv = xp[i];
    const float4 wv = wp[i];
    acc += xv.x * wv.x + xv.y * wv.y + xv.z * wv.z + xv.w * wv.w;
  }
#pragma unroll
  for (int off = 32; off > 0; off >>= 1)
    acc += __shfl_xor(acc, off, 64);

  if (lane == 0) {
    const float z = (acc + b[0]) * 0.01f;
    scores[row] = 1.0f / (1.0f + expf(-z));
  }
}

// ---------------------------------------------------------------------------
// Kernel 2: per-class selection. 16 blocks (one per class) x 512 threads.
// Phase A: member list (ascending) via chunked ballot + block prefix sum.
// Phase B: mean of the 512 member scores (double accumulate -> float).
// Phase C: exact top_k order: key = mean - score desc, ties by position asc.
//          O(n^2) rank-by-counting; LDS broadcast reads, conflict-free.
// ---------------------------------------------------------------------------
__global__ __launch_bounds__(512) void select_kernel(
    const int* __restrict__ mask, const float* __restrict__ scores,
    int* __restrict__ sel_idx, float* __restrict__ sel_val) {
  const int cls  = blockIdx.x;
  const int tid  = threadIdx.x;
  const int lane = tid & 63;
  const int wave = tid >> 6;     // 8 waves

  __shared__ int   members[PER_CLASS];
  __shared__ float ssc[PER_CLASS];
  __shared__ int   wave_tot[8];
  __shared__ int   running;
  __shared__ double wsum[8];
  __shared__ float meanf;

  if (tid == 0) running = 0;
  __syncthreads();

  // Phase A: gather member indices in ascending order
  for (int chunk = 0; chunk < NN; chunk += 512) {
    const int i = chunk + tid;
    const bool flag = (mask[i] == cls);
    const unsigned long long bal = __ballot(flag);
    const int pre = __popcll(bal & ((1ull << lane) - 1ull));
    if (lane == 0) wave_tot[wave] = __popcll(bal);
    __syncthreads();
    int woff = 0;
    for (int w = 0; w < wave; ++w) woff += wave_tot[w];
    const int pos = running + woff + pre;
    if (flag) members[pos] = i;
    __syncthreads();           // everyone done reading `running`
    if (tid == 0) {
      int tot = 0;
      for (int w = 0; w < 8; ++w) tot += wave_tot[w];
      running += tot;
    }
    __syncthreads();           // updated `running` visible next chunk
  }

  // Phase B: member scores + mean
  ssc[tid] = scores[members[tid]];
  __syncthreads();
  double v = (double)ssc[tid];
#pragma unroll
  for (int off = 32; off > 0; off >>= 1)
    v += __shfl_xor(v, off, 64);
  if (lane == 0) wsum[wave] = v;
  __syncthreads();
  if (tid == 0) {
    double s = 0.0;
    for (int w = 0; w < 8; ++w) s += wsum[w];
    meanf = (float)(s / (double)PER_CLASS);
  }
  __syncthreads();

  // Phase C: rank by (key desc, position asc) — exact lax.top_k order
  const float m = meanf;
  const float mykey = m - ssc[tid];
  int rank = 0;
  for (int u = 0; u < PER_CLASS; ++u) {
    const float ku = m - ssc[u];
    rank += (ku > mykey) || (ku == mykey && u < tid);
  }
  if (rank < KK) {
    sel_val[cls * KK + rank] = ssc[tid];
    sel_idx[cls * KK + rank] = members[tid];
  }
}

// ---------------------------------------------------------------------------
// Kernel 3 (fused): one block (512 threads = 8 waves) per output row r.
//   M_out[r][c] = M[idx[r]][idx[c]]  (stage 32 KB row in LDS, gather, store)
//   X_out[r]    = X[idx[r]] * val[r] (issued before the barrier -> overlaps)
//   mask_out[r] = r >> 8  (row r was selected from class r/KK by construction
//                          — no memory read needed)
// 512 thr + 32 KB LDS -> 4 blocks/CU = 32 waves/CU (full occupancy) on the
// HBM-dominant dispatch. Nontemporal on read-once/write-once streams.
// ---------------------------------------------------------------------------
__global__ __launch_bounds__(512) void gather_kernel(
    const float* __restrict__ M, const float* __restrict__ X,
    const int* __restrict__ sel_idx, const float* __restrict__ sel_val,
    float* __restrict__ m_out, float* __restrict__ x_out,
    float* __restrict__ mask_out) {
  __shared__ float row[NN];    // 32 KB
  const int r   = blockIdx.x;
  const int src = sel_idx[r];

  // Stage M row (32 KB, coalesced, read-once -> nontemporal)
  const vfloat4* mp = (const vfloat4*)(M + (size_t)src * NN);
  vfloat4* rp = (vfloat4*)row;
#pragma unroll
  for (int k = 0; k < 4; ++k) {                // 2048 float4s / 512 thr
    const int i = k * 512 + threadIdx.x;
    rp[i] = __builtin_nontemporal_load(&mp[i]);
  }

  // X row gather+scale (2 KB) — overlaps the M stage, before the barrier
  if (threadIdx.x < 128) {
    const float v = sel_val[r];
    const vfloat4 x =
        ((const vfloat4*)(X + (size_t)src * IN_DIM))[threadIdx.x];
    const vfloat4 o = x * v;
    __builtin_nontemporal_store(
        o, (vfloat4*)(x_out + (size_t)r * IN_DIM) + threadIdx.x);
  }
  if (threadIdx.x == 0) mask_out[r] = (float)(r >> 8);

  __syncthreads();

  // Gather 4096 columns from LDS, store coalesced float4 (write-once)
  vfloat4* out = (vfloat4*)(m_out + (size_t)r * NSEL);
  const int4* idx4 = (const int4*)sel_idx;
#pragma unroll
  for (int k = 0; k < 2; ++k) {                // 1024 float4s / 512 thr
    const int c4 = k * 512 + threadIdx.x;      // float4 index
    const int4 id = idx4[c4];
    vfloat4 o;
    o.x = row[id.x]; o.y = row[id.y]; o.z = row[id.z]; o.w = row[id.w];
    __builtin_nontemporal_store(o, &out[c4]);
  }
}

// ---------------------------------------------------------------------------
extern "C" void kernel_launch(void* const* d_in, const int* in_sizes, int n_in,
                              void* d_out, int out_size, void* d_ws, size_t ws_size,
                              hipStream_t stream) {
  const float* M    = (const float*)d_in[0];   // [1,8192,8192]
  const float* X    = (const float*)d_in[1];   // [1,8192,512]
  const int*   mask = (const int*)  d_in[2];   // [1,8192]
  const float* W    = (const float*)d_in[3];   // [1,512]
  const float* b    = (const float*)d_in[4];   // [1]

  float* out = (float*)d_out;
  // Output layout (flat, return order): M_out | X_out | mask_out
  float* m_out    = out;                                   // 4096*4096
  float* x_out    = out + (size_t)NSEL * NSEL;             // 4096*512
  float* mask_out = x_out + (size_t)NSEL * IN_DIM;         // 4096

  // Workspace layout
  float* scores  = (float*)d_ws;                                    // 8192 f
  int*   sel_idx = (int*)((char*)d_ws + NN * sizeof(float));        // 4096 i
  float* sel_val = (float*)((char*)d_ws + NN * sizeof(float)
                                        + NSEL * sizeof(int));      // 4096 f

  // 1) scores: 4 waves/block -> 4 rows/block -> 2048 blocks
  scores_kernel<<<NN / 4, 256, 0, stream>>>(X, W, b, scores);

  // 2) per-class top-k selection
  select_kernel<<<NUM_CLASSES, 512, 0, stream>>>(mask, scores, sel_idx, sel_val);

  // 3) fused M/X/mask gather
  gather_kernel<<<NSEL, 512, 0, stream>>>(M, X, sel_idx, sel_val,
                                          m_out, x_out, mask_out);
}